// Round 4
// baseline (441.554 us; speedup 1.0000x reference)
//
#include <hip/hip_runtime.h>
#include <stdint.h>

#define D_MODEL 1024
#define N_EXP   8
#define HIDDEN  2048
#define TOPK    2

#define BK    64
#define BM    256          // M-tile both GEMMs
#define BN1   64           // gemm1 N-tile (dual B1/B3)
#define BN2   64           // gemm2 N-tile
#define NT1   (D_MODEL / BK)   // 16
#define NT2   (HIDDEN / BK)    // 32

typedef short bf16x8 __attribute__((ext_vector_type(8)));
typedef float f32x4 __attribute__((ext_vector_type(4)));

__device__ __forceinline__ unsigned short f2bf(float f) {
    union { float f; unsigned u; } v; v.f = f;
    unsigned r = v.u + 0x7fffu + ((v.u >> 16) & 1u);
    return (unsigned short)(r >> 16);
}

__device__ __forceinline__ float bf2f(unsigned short u) {
    union { unsigned u; float f; } v; v.u = (unsigned)u << 16; return v.f;
}

__device__ __forceinline__ void gload_lds16(const void* g, void* l) {
    __builtin_amdgcn_global_load_lds(
        (const __attribute__((address_space(1))) void*)g,
        (__attribute__((address_space(3))) void*)l, 16, 0, 0);
}

// ---------------- convert x to bf16 ----------------
__global__ void k_cvt_x(const float* __restrict__ x, unsigned short* __restrict__ xb, int n8) {
    int i = blockIdx.x * blockDim.x + threadIdx.x;
    if (i >= n8) return;
    size_t base = (size_t)i * 8;
    float4 a = *(const float4*)(x + base);
    float4 b = *(const float4*)(x + base + 4);
    union { unsigned short us[8]; uint4 v; } pk;
    pk.us[0] = f2bf(a.x); pk.us[1] = f2bf(a.y); pk.us[2] = f2bf(a.z); pk.us[3] = f2bf(a.w);
    pk.us[4] = f2bf(b.x); pk.us[5] = f2bf(b.y); pk.us[6] = f2bf(b.z); pk.us[7] = f2bf(b.w);
    *(uint4*)(xb + base) = pk.v;
}

// ---------------- convert + transpose weights: in [E][Rr][Cc] f32 -> out [E][Cc][Rr] bf16 ----------------
__global__ __launch_bounds__(256) void k_cvt_t(const float* __restrict__ in,
                                               unsigned short* __restrict__ out,
                                               int Rr, int Cc) {
    __shared__ unsigned short t[64][66];
    const size_t eb = (size_t)blockIdx.z * Rr * Cc;
    const int r0 = blockIdx.y * 64, c0 = blockIdx.x * 64;
    const int tid = threadIdx.x;
#pragma unroll
    for (int i = 0; i < 16; ++i) {
        int idx = i * 256 + tid;
        int r = idx >> 6, c = idx & 63;
        t[c][r] = f2bf(in[eb + (size_t)(r0 + r) * Cc + c0 + c]);
    }
    __syncthreads();
#pragma unroll
    for (int i = 0; i < 2; ++i) {
        int idx = i * 256 + tid;
        int hc = idx >> 3, d8 = (idx & 7) * 8;
        bf16x8 v = *(const bf16x8*)(&t[hc][d8]);
        *(bf16x8*)(&out[eb + (size_t)(c0 + hc) * Rr + r0 + d8]) = v;
    }
}

// ---------------- router: logits -> softmax -> top2 ----------------
__global__ void k_router(const float* __restrict__ x, const float* __restrict__ wr,
                         int* __restrict__ tok_e, float* __restrict__ tok_w,
                         int* __restrict__ counts, int T) {
    int t = blockIdx.x * (blockDim.x >> 6) + (threadIdx.x >> 6);
    int lane = threadIdx.x & 63;
    if (t >= T) return;
    const float* xr = x + (size_t)t * D_MODEL;
    float acc[N_EXP];
#pragma unroll
    for (int e = 0; e < N_EXP; ++e) acc[e] = 0.f;
    for (int d = lane; d < D_MODEL; d += 64) {
        float xv = xr[d];
        const float* w = wr + (size_t)d * N_EXP;
#pragma unroll
        for (int e = 0; e < N_EXP; ++e) acc[e] += xv * w[e];
    }
#pragma unroll
    for (int off = 32; off > 0; off >>= 1) {
#pragma unroll
        for (int e = 0; e < N_EXP; ++e) acc[e] += __shfl_down(acc[e], off, 64);
    }
    if (lane == 0) {
        float mx = acc[0];
#pragma unroll
        for (int e = 1; e < N_EXP; ++e) mx = fmaxf(mx, acc[e]);
        float p[N_EXP], den = 0.f;
#pragma unroll
        for (int e = 0; e < N_EXP; ++e) { p[e] = __expf(acc[e] - mx); den += p[e]; }
        float inv = 1.f / den;
        int e0 = 0; float v0 = acc[0];
#pragma unroll
        for (int e = 1; e < N_EXP; ++e) if (acc[e] > v0) { v0 = acc[e]; e0 = e; }
        int e1 = -1; float v1 = -1e30f;
#pragma unroll
        for (int e = 0; e < N_EXP; ++e) if (e != e0 && acc[e] > v1) { v1 = acc[e]; e1 = e; }
        tok_e[2 * t] = e0;     tok_w[2 * t] = p[e0] * inv;
        tok_e[2 * t + 1] = e1; tok_w[2 * t + 1] = p[e1] * inv;
        atomicAdd(&counts[e0], 1);
        atomicAdd(&counts[e1], 1);
    }
}

// ---------------- prefix scan of expert counts ----------------
__global__ void k_scan(const int* __restrict__ counts, int* __restrict__ offs, int* __restrict__ curs) {
    if (threadIdx.x == 0) {
        int s = 0;
        for (int e = 0; e < N_EXP; ++e) { offs[e] = s; curs[e] = s; s += counts[e]; }
        offs[N_EXP] = s;
    }
}

// ---------------- scatter tokens into expert-grouped rows ----------------
__global__ void k_scatter(const int* __restrict__ tok_e, const float* __restrict__ tok_w,
                          int* __restrict__ curs, int* __restrict__ row_token,
                          float* __restrict__ row_weight, int* __restrict__ tok_pos, int T) {
    int t = blockIdx.x * blockDim.x + threadIdx.x;
    if (t >= T) return;
#pragma unroll
    for (int k = 0; k < TOPK; ++k) {
        int e = tok_e[2 * t + k];
        int pos = atomicAdd(&curs[e], 1);
        row_token[pos] = t;
        row_weight[pos] = tok_w[2 * t + k];
        tok_pos[2 * t + k] = pos;
    }
}

// ---------------- GEMM1: h = silu(x@w1)*(x@w3)*w_route; 512 thr, 3-buf counted-vmcnt ----------------
__global__ __launch_bounds__(512) void k_gemm1(
    const unsigned short* __restrict__ xb,    // [T][D] bf16
    const unsigned short* __restrict__ w1t,   // [E][H][D] bf16
    const unsigned short* __restrict__ w3t,   // [E][H][D] bf16
    const int* __restrict__ row_token,
    const float* __restrict__ row_weight,
    const int* __restrict__ offs,
    unsigned short* __restrict__ h)           // [R][H] bf16
{
    __shared__ unsigned short A[3][BM * BK];    // 3 x 32 KB
    __shared__ unsigned short B1[3][BN1 * BK];  // 3 x 8 KB
    __shared__ unsigned short B3[3][BN1 * BK];  // 3 x 8 KB

    const int e = blockIdx.z;
    const int off = offs[e];
    const int ne = offs[e + 1] - off;
    const int m0 = blockIdx.y * BM;
    if (m0 >= ne) return;
    const int n0 = blockIdx.x * BN1;

    const int tid = threadIdx.x;
    const int lane = tid & 63, wid = tid >> 6;   // 8 waves
    const int wm = wid >> 1, wn = wid & 1;       // 4M x 2N

    // A staging: 4 gload_lds / thread (2048 chunks of 16B)
    const unsigned short* asrc[4];
    unsigned aoff[4];
#pragma unroll
    for (int q = 0; q < 4; ++q) {
        int i = wid * 4 + q;            // 0..31
        int c = i * 64 + lane;          // chunk id
        int m = c >> 3, kc = c & 7;
        int kcs = kc ^ (m & 7);
        int gm = m0 + m;
        int gmc = gm < ne ? gm : (ne - 1);
        int tok = row_token[off + gmc];
        asrc[q] = xb + (size_t)tok * D_MODEL + kcs * 8;
        aoff[q] = (unsigned)i * 512u;   // ushort offset
    }
    // B staging: 1 gload_lds / thread per matrix (512 chunks)
    int bc = wid * 64 + lane;
    int bn = bc >> 3, bkc = bc & 7;
    int bkcs = bkc ^ (bn & 7);
    const unsigned short* b1s = w1t + ((size_t)e * HIDDEN + n0 + bn) * D_MODEL + bkcs * 8;
    const unsigned short* b3s = w3t + ((size_t)e * HIDDEN + n0 + bn) * D_MODEL + bkcs * 8;
    unsigned boff = (unsigned)wid * 512u;

    f32x4 acc1[4][2], acc3[4][2];
    const f32x4 zf = {0.f, 0.f, 0.f, 0.f};
#pragma unroll
    for (int mi = 0; mi < 4; ++mi)
#pragma unroll
        for (int ni = 0; ni < 2; ++ni) { acc1[mi][ni] = zf; acc3[mi][ni] = zf; }

    // prologue: stage tiles 0,1 (L=6 loads each per thread)
#pragma unroll
    for (int t = 0; t < 2; ++t) {
#pragma unroll
        for (int q = 0; q < 4; ++q) gload_lds16(asrc[q] + t * BK, &A[t][aoff[q]]);
        gload_lds16(b1s + t * BK, &B1[t][boff]);
        gload_lds16(b3s + t * BK, &B3[t][boff]);
    }

    int cur = 0;
#pragma unroll 1
    for (int kt = 0; kt < NT1; ++kt) {
        if (kt == NT1 - 1) asm volatile("s_waitcnt vmcnt(0)" ::: "memory");
        else               asm volatile("s_waitcnt vmcnt(6)" ::: "memory");
        __builtin_amdgcn_s_barrier();
        __builtin_amdgcn_sched_barrier(0);
        if (kt + 2 < NT1) {
            const int nb = (cur + 2 >= 3) ? (cur - 1) : (cur + 2);
            const int ko = (kt + 2) * BK;
#pragma unroll
            for (int q = 0; q < 4; ++q) gload_lds16(asrc[q] + ko, &A[nb][aoff[q]]);
            gload_lds16(b1s + ko, &B1[nb][boff]);
            gload_lds16(b3s + ko, &B3[nb][boff]);
        }
#pragma unroll
        for (int kf = 0; kf < 2; ++kf) {
            bf16x8 a[4], b1f[2], b3f[2];
            int ke = kf * 32 + (lane >> 4) * 8;
#pragma unroll
            for (int mi = 0; mi < 4; ++mi) {
                int m = wm * 64 + mi * 16 + (lane & 15);
                a[mi] = *(const bf16x8*)(&A[cur][m * BK + (ke ^ ((m & 7) * 8))]);
            }
#pragma unroll
            for (int ni = 0; ni < 2; ++ni) {
                int n = wn * 32 + ni * 16 + (lane & 15);
                int eo = n * BK + (ke ^ ((n & 7) * 8));
                b1f[ni] = *(const bf16x8*)(&B1[cur][eo]);
                b3f[ni] = *(const bf16x8*)(&B3[cur][eo]);
            }
            __builtin_amdgcn_s_setprio(1);
#pragma unroll
            for (int mi = 0; mi < 4; ++mi)
#pragma unroll
                for (int ni = 0; ni < 2; ++ni) {
                    acc1[mi][ni] = __builtin_amdgcn_mfma_f32_16x16x32_bf16(a[mi], b1f[ni], acc1[mi][ni], 0, 0, 0);
                    acc3[mi][ni] = __builtin_amdgcn_mfma_f32_16x16x32_bf16(a[mi], b3f[ni], acc3[mi][ni], 0, 0, 0);
                }
            __builtin_amdgcn_s_setprio(0);
        }
        cur = (cur == 2) ? 0 : (cur + 1);
    }

    // epilogue: h = silu(acc1)*acc3*w
#pragma unroll
    for (int mi = 0; mi < 4; ++mi) {
#pragma unroll
        for (int r = 0; r < 4; ++r) {
            int m = wm * 64 + mi * 16 + (lane >> 4) * 4 + r;
            int gm = m0 + m;
            if (gm < ne) {
                float wgt = row_weight[off + gm];
                size_t rowbase = (size_t)(off + gm) * HIDDEN + n0;
#pragma unroll
                for (int ni = 0; ni < 2; ++ni) {
                    float v1 = acc1[mi][ni][r], v3 = acc3[mi][ni][r];
                    float sv = v1 / (1.f + __expf(-v1));
                    int n = wn * 32 + ni * 16 + (lane & 15);
                    h[rowbase + n] = f2bf(sv * v3 * wgt);
                }
            }
        }
    }
}

// ---------------- GEMM2: y = h @ w2; 512 thr, 3-buf counted-vmcnt ----------------
__global__ __launch_bounds__(512) void k_gemm2(
    const unsigned short* __restrict__ h,    // [R][H] bf16
    const unsigned short* __restrict__ w2t,  // [E][D][H] bf16
    const int* __restrict__ offs,
    unsigned short* __restrict__ y)          // [R][D] bf16
{
    __shared__ unsigned short A[3][BM * BK];    // 3 x 32 KB
    __shared__ unsigned short B[3][BN2 * BK];   // 3 x 8 KB

    const int e = blockIdx.z;
    const int off = offs[e];
    const int ne = offs[e + 1] - off;
    const int m0 = blockIdx.y * BM;
    if (m0 >= ne) return;
    const int n0 = blockIdx.x * BN2;

    const int tid = threadIdx.x;
    const int lane = tid & 63, wid = tid >> 6;
    const int wm = wid >> 1, wn = wid & 1;

    const unsigned short* asrc[4];
    unsigned aoff[4];
#pragma unroll
    for (int q = 0; q < 4; ++q) {
        int i = wid * 4 + q;
        int c = i * 64 + lane;
        int m = c >> 3, kc = c & 7;
        int kcs = kc ^ (m & 7);
        int gm = m0 + m;
        int gmc = gm < ne ? gm : (ne - 1);
        asrc[q] = h + (size_t)(off + gmc) * HIDDEN + kcs * 8;
        aoff[q] = (unsigned)i * 512u;
    }
    int bc = wid * 64 + lane;
    int bn = bc >> 3, bkc = bc & 7;
    int bkcs = bkc ^ (bn & 7);
    const unsigned short* bs = w2t + ((size_t)e * D_MODEL + n0 + bn) * HIDDEN + bkcs * 8;
    unsigned boff = (unsigned)wid * 512u;

    f32x4 acc[4][2];
    const f32x4 zf = {0.f, 0.f, 0.f, 0.f};
#pragma unroll
    for (int mi = 0; mi < 4; ++mi)
#pragma unroll
        for (int ni = 0; ni < 2; ++ni) acc[mi][ni] = zf;

#pragma unroll
    for (int t = 0; t < 2; ++t) {
#pragma unroll
        for (int q = 0; q < 4; ++q) gload_lds16(asrc[q] + t * BK, &A[t][aoff[q]]);
        gload_lds16(bs + t * BK, &B[t][boff]);
    }

    int cur = 0;
#pragma unroll 1
    for (int kt = 0; kt < NT2; ++kt) {
        if (kt == NT2 - 1) asm volatile("s_waitcnt vmcnt(0)" ::: "memory");
        else               asm volatile("s_waitcnt vmcnt(5)" ::: "memory");
        __builtin_amdgcn_s_barrier();
        __builtin_amdgcn_sched_barrier(0);
        if (kt + 2 < NT2) {
            const int nb = (cur + 2 >= 3) ? (cur - 1) : (cur + 2);
            const int ko = (kt + 2) * BK;
#pragma unroll
            for (int q = 0; q < 4; ++q) gload_lds16(asrc[q] + ko, &A[nb][aoff[q]]);
            gload_lds16(bs + ko, &B[nb][boff]);
        }
#pragma unroll
        for (int kf = 0; kf < 2; ++kf) {
            bf16x8 a[4], b[2];
            int ke = kf * 32 + (lane >> 4) * 8;
#pragma unroll
            for (int mi = 0; mi < 4; ++mi) {
                int m = wm * 64 + mi * 16 + (lane & 15);
                a[mi] = *(const bf16x8*)(&A[cur][m * BK + (ke ^ ((m & 7) * 8))]);
            }
#pragma unroll
            for (int ni = 0; ni < 2; ++ni) {
                int n = wn * 32 + ni * 16 + (lane & 15);
                b[ni] = *(const bf16x8*)(&B[cur][n * BK + (ke ^ ((n & 7) * 8))]);
            }
            __builtin_amdgcn_s_setprio(1);
#pragma unroll
            for (int mi = 0; mi < 4; ++mi)
#pragma unroll
                for (int ni = 0; ni < 2; ++ni)
                    acc[mi][ni] = __builtin_amdgcn_mfma_f32_16x16x32_bf16(a[mi], b[ni], acc[mi][ni], 0, 0, 0);
            __builtin_amdgcn_s_setprio(0);
        }
        cur = (cur == 2) ? 0 : (cur + 1);
    }

#pragma unroll
    for (int mi = 0; mi < 4; ++mi) {
#pragma unroll
        for (int r = 0; r < 4; ++r) {
            int m = wm * 64 + mi * 16 + (lane >> 4) * 4 + r;
            int gm = m0 + m;
            if (gm < ne) {
                size_t rowbase = (size_t)(off + gm) * D_MODEL + n0;
#pragma unroll
                for (int ni = 0; ni < 2; ++ni) {
                    int n = wn * 32 + ni * 16 + (lane & 15);
                    y[rowbase + n] = f2bf(acc[mi][ni][r]);
                }
            }
        }
    }
}

// ---------------- combine: out[t] = y[pos0] + y[pos1] ----------------
__global__ void k_combine(const unsigned short* __restrict__ y,
                          const int* __restrict__ tok_pos,
                          float* __restrict__ out, int n8) {
    int i = blockIdx.x * blockDim.x + threadIdx.x;
    if (i >= n8) return;
    int t = i >> 7;
    int c = (i & 127) * 8;
    int p0 = tok_pos[2 * t];
    int p1 = tok_pos[2 * t + 1];
    bf16x8 v0 = *(const bf16x8*)(y + (size_t)p0 * D_MODEL + c);
    bf16x8 v1 = *(const bf16x8*)(y + (size_t)p1 * D_MODEL + c);
    float* op = out + (size_t)t * D_MODEL + c;
    float4 o0, o1;
    o0.x = bf2f((unsigned short)v0[0]) + bf2f((unsigned short)v1[0]);
    o0.y = bf2f((unsigned short)v0[1]) + bf2f((unsigned short)v1[1]);
    o0.z = bf2f((unsigned short)v0[2]) + bf2f((unsigned short)v1[2]);
    o0.w = bf2f((unsigned short)v0[3]) + bf2f((unsigned short)v1[3]);
    o1.x = bf2f((unsigned short)v0[4]) + bf2f((unsigned short)v1[4]);
    o1.y = bf2f((unsigned short)v0[5]) + bf2f((unsigned short)v1[5]);
    o1.z = bf2f((unsigned short)v0[6]) + bf2f((unsigned short)v1[6]);
    o1.w = bf2f((unsigned short)v0[7]) + bf2f((unsigned short)v1[7]);
    *(float4*)op = o0;
    *(float4*)(op + 4) = o1;
}

extern "C" void kernel_launch(void* const* d_in, const int* in_sizes, int n_in,
                              void* d_out, int out_size, void* d_ws, size_t ws_size,
                              hipStream_t stream) {
    const float* x  = (const float*)d_in[0];
    const float* wr = (const float*)d_in[1];
    const float* w1 = (const float*)d_in[2];
    const float* w3 = (const float*)d_in[3];
    const float* w2 = (const float*)d_in[4];
    float* out = (float*)d_out;

    const int T = in_sizes[0] / D_MODEL;   // 4096
    const int R = T * TOPK;                // 8192

    char* ws = (char*)d_ws;
    size_t o = 0;
    unsigned short* xb  = (unsigned short*)(ws + o); o += (size_t)T * D_MODEL * 2;
    unsigned short* h   = (unsigned short*)(ws + o); o += (size_t)R * HIDDEN * 2;
    unsigned short* w1t = (unsigned short*)(ws + o); o += (size_t)N_EXP * D_MODEL * HIDDEN * 2;
    unsigned short* w3t = (unsigned short*)(ws + o); o += (size_t)N_EXP * D_MODEL * HIDDEN * 2;
    unsigned short* w2t = (unsigned short*)(ws + o); o += (size_t)N_EXP * HIDDEN * D_MODEL * 2;
    int*   row_token  = (int*)(ws + o);   o += (size_t)R * 4;
    float* row_weight = (float*)(ws + o); o += (size_t)R * 4;
    int*   tok_e      = (int*)(ws + o);   o += (size_t)2 * T * 4;
    float* tok_w      = (float*)(ws + o); o += (size_t)2 * T * 4;
    int*   tok_pos    = (int*)(ws + o);   o += (size_t)2 * T * 4;
    int*   counts     = (int*)(ws + o);   o += 16 * 4;
    int*   offs       = (int*)(ws + o);   o += 16 * 4;
    int*   curs       = (int*)(ws + o);   o += 16 * 4;

    // y aliases w1t (dead after gemm1)
    unsigned short* y = w1t;

    hipMemsetAsync(counts, 0, 16 * 4, stream);

    int n8 = T * D_MODEL / 8;
    k_cvt_x<<<(n8 + 255) / 256, 256, 0, stream>>>(x, xb, n8);

    dim3 gt13(HIDDEN / 64, D_MODEL / 64, N_EXP);
    k_cvt_t<<<gt13, 256, 0, stream>>>(w1, w1t, D_MODEL, HIDDEN);
    k_cvt_t<<<gt13, 256, 0, stream>>>(w3, w3t, D_MODEL, HIDDEN);
    dim3 gt2(D_MODEL / 64, HIDDEN / 64, N_EXP);
    k_cvt_t<<<gt2, 256, 0, stream>>>(w2, w2t, HIDDEN, D_MODEL);

    k_router<<<(T + 3) / 4, 256, 0, stream>>>(x, wr, tok_e, tok_w, counts, T);
    k_scan<<<1, 64, 0, stream>>>(counts, offs, curs);
    k_scatter<<<(T + 255) / 256, 256, 0, stream>>>(tok_e, tok_w, curs, row_token, row_weight, tok_pos, T);

    // ne <= T = 4096 -> at most 16 m-tiles of 256
    dim3 g1(HIDDEN / BN1, 16, N_EXP);
    k_gemm1<<<g1, 512, 0, stream>>>(xb, w1t, w3t, row_token, row_weight, offs, h);

    dim3 g2(D_MODEL / BN2, 16, N_EXP);
    k_gemm2<<<g2, 512, 0, stream>>>(h, w2t, offs, y);

    k_combine<<<(n8 + 255) / 256, 256, 0, stream>>>(y, tok_pos, out, n8);
}

// Round 6
// 339.360 us; speedup vs baseline: 1.3011x; 1.3011x over previous
//
#include <hip/hip_runtime.h>
#include <stdint.h>

#define D_MODEL 1024
#define N_EXP   8
#define HIDDEN  2048
#define TOPK    2

#define BK    64
#define BM    128
#define BN1   64            // gemm1 (dual B1/B3)
#define BN2   128           // gemm2
#define NT1   (D_MODEL / BK)   // 16
#define NT2   (HIDDEN / BK)    // 32
#define MT_MAX 72              // max padded m-tiles: (8192 + 8*127)/128
#define G1_GRID (MT_MAX * (HIDDEN / BN1))   // 72*32 = 2304
#define G2_GRID (MT_MAX * (D_MODEL / BN2))  // 72*8  = 576

typedef short bf16x8 __attribute__((ext_vector_type(8)));
typedef float f32x4 __attribute__((ext_vector_type(4)));

__device__ __forceinline__ unsigned short f2bf(float f) {
    union { float f; unsigned u; } v; v.f = f;
    unsigned r = v.u + 0x7fffu + ((v.u >> 16) & 1u);
    return (unsigned short)(r >> 16);
}

__device__ __forceinline__ float bf2f(unsigned short u) {
    union { unsigned u; float f; } v; v.u = (unsigned)u << 16; return v.f;
}

__device__ __forceinline__ void gload_lds16(const void* g, void* l) {
    __builtin_amdgcn_global_load_lds(
        (const __attribute__((address_space(1))) void*)g,
        (__attribute__((address_space(3))) void*)l, 16, 0, 0);
}

// ---------------- fused router + x->bf16 convert ----------------
__global__ __launch_bounds__(256) void k_router_cvt(
    const float* __restrict__ x, const float* __restrict__ wr,
    unsigned short* __restrict__ xb,
    int* __restrict__ tok_e, float* __restrict__ tok_w,
    int* __restrict__ counts, int T)
{
    int t = blockIdx.x * 4 + (threadIdx.x >> 6);
    int lane = threadIdx.x & 63;
    if (t >= T) return;
    const float4* xr = (const float4*)(x + (size_t)t * D_MODEL);
    float acc[N_EXP];
#pragma unroll
    for (int e = 0; e < N_EXP; ++e) acc[e] = 0.f;
#pragma unroll
    for (int j = 0; j < 4; ++j) {
        int c = j * 64 + lane;              // float4 chunk within row
        float4 v = xr[c];
        ushort4 pk;
        pk.x = f2bf(v.x); pk.y = f2bf(v.y); pk.z = f2bf(v.z); pk.w = f2bf(v.w);
        *(ushort4*)(xb + (size_t)t * D_MODEL + c * 4) = pk;
        const float4* w4 = (const float4*)(wr + (size_t)c * 4 * N_EXP);
#pragma unroll
        for (int k = 0; k < 4; ++k) {
            float xv = (k == 0) ? v.x : (k == 1) ? v.y : (k == 2) ? v.z : v.w;
            float4 wa = w4[k * 2], wb = w4[k * 2 + 1];
            acc[0] += xv * wa.x; acc[1] += xv * wa.y; acc[2] += xv * wa.z; acc[3] += xv * wa.w;
            acc[4] += xv * wb.x; acc[5] += xv * wb.y; acc[6] += xv * wb.z; acc[7] += xv * wb.w;
        }
    }
#pragma unroll
    for (int off = 32; off > 0; off >>= 1) {
#pragma unroll
        for (int e = 0; e < N_EXP; ++e) acc[e] += __shfl_down(acc[e], off, 64);
    }
    if (lane == 0) {
        float mx = acc[0];
#pragma unroll
        for (int e = 1; e < N_EXP; ++e) mx = fmaxf(mx, acc[e]);
        float p[N_EXP], den = 0.f;
#pragma unroll
        for (int e = 0; e < N_EXP; ++e) { p[e] = __expf(acc[e] - mx); den += p[e]; }
        float inv = 1.f / den;
        int e0 = 0; float v0 = acc[0];
#pragma unroll
        for (int e = 1; e < N_EXP; ++e) if (acc[e] > v0) { v0 = acc[e]; e0 = e; }
        int e1 = -1; float v1 = -1e30f;
#pragma unroll
        for (int e = 0; e < N_EXP; ++e) if (e != e0 && acc[e] > v1) { v1 = acc[e]; e1 = e; }
        tok_e[2 * t] = e0;     tok_w[2 * t] = p[e0] * inv;
        tok_e[2 * t + 1] = e1; tok_w[2 * t + 1] = p[e1] * inv;
        atomicAdd(&counts[e0], 1);
        atomicAdd(&counts[e1], 1);
    }
}

// ---------------- all 3 weight transposes in one launch ----------------
__global__ __launch_bounds__(256) void k_cvt3(
    const float* __restrict__ w1, const float* __restrict__ w3, const float* __restrict__ w2,
    unsigned short* __restrict__ w1t, unsigned short* __restrict__ w3t, unsigned short* __restrict__ w2t)
{
    __shared__ unsigned short t[64][68];
    const int z = blockIdx.y;
    const int mat = z >> 3, e = z & 7;
    const float* in; unsigned short* out; int Rr, Cc;
    if (mat == 0)      { in = w1; out = w1t; Rr = D_MODEL; Cc = HIDDEN; }
    else if (mat == 1) { in = w3; out = w3t; Rr = D_MODEL; Cc = HIDDEN; }
    else               { in = w2; out = w2t; Rr = HIDDEN; Cc = D_MODEL; }
    const size_t eb = (size_t)e * Rr * Cc;
    const int tpc = Cc >> 6;
    const int bx = blockIdx.x;
    const int c0 = (bx % tpc) * 64, r0 = (bx / tpc) * 64;
    const int tid = threadIdx.x;
#pragma unroll
    for (int p = 0; p < 4; ++p) {
        int li = p * 256 + tid;
        int r = li >> 4, q = li & 15;
        float4 v = *(const float4*)(in + eb + (size_t)(r0 + r) * Cc + c0 + q * 4);
        t[q * 4 + 0][r] = f2bf(v.x);
        t[q * 4 + 1][r] = f2bf(v.y);
        t[q * 4 + 2][r] = f2bf(v.z);
        t[q * 4 + 3][r] = f2bf(v.w);
    }
    __syncthreads();
#pragma unroll
    for (int p = 0; p < 2; ++p) {
        int li = p * 256 + tid;
        int c = li >> 3, j = li & 7;
        bf16x8 v = *(const bf16x8*)(&t[c][j * 8]);
        *(bf16x8*)(&out[eb + (size_t)(c0 + c) * Rr + r0 + j * 8]) = v;
    }
}

// ---------------- scan (padded to BM) + scatter, single block ----------------
__global__ void k_scan_scatter(const int* __restrict__ counts,
                               const int* __restrict__ tok_e, const float* __restrict__ tok_w,
                               int* __restrict__ offs,
                               int* __restrict__ row_token, float* __restrict__ row_weight,
                               int* __restrict__ tok_pos, int T) {
    __shared__ int scurs[N_EXP];
    if (threadIdx.x == 0) {
        int s = 0;
        for (int e = 0; e < N_EXP; ++e) {
            offs[e] = s; scurs[e] = s;
            s += ((counts[e] + BM - 1) / BM) * BM;   // pad to BM
        }
        offs[N_EXP] = s;
    }
    __syncthreads();
    for (int i = threadIdx.x; i < 2 * T; i += blockDim.x) {
        int e = tok_e[i];
        int pos = atomicAdd(&scurs[e], 1);
        row_token[pos] = i >> 1;
        row_weight[pos] = tok_w[i];
        tok_pos[i] = pos;
    }
}

// ---------------- GEMM1: h = silu(x@w1)*(x@w3)*w_route (compact grid, padded) ----------------
__global__ __launch_bounds__(256) void k_gemm1(
    const unsigned short* __restrict__ xb,    // [T][D] bf16
    const unsigned short* __restrict__ w1t,   // [E][H][D] bf16
    const unsigned short* __restrict__ w3t,   // [E][H][D] bf16
    const int* __restrict__ row_token,
    const float* __restrict__ row_weight,
    const int* __restrict__ offs,             // [E+1] padded
    unsigned short* __restrict__ h)           // [Rp][H] bf16
{
    __shared__ unsigned short A[BM * BK];     // 16 KB
    __shared__ unsigned short B1[BN1 * BK];   // 8 KB
    __shared__ unsigned short B3[BN1 * BK];   // 8 KB

    // bijective XCD-chunked swizzle, then flat -> (e, nt, mt), mt fastest
    const int b = blockIdx.x;
    const int bs = (b & 7) * (G1_GRID / 8) + (b >> 3);
    int e = 0, mt = 0, nt = 0, found = 0, at = 0;
#pragma unroll
    for (int ee = 0; ee < N_EXP; ++ee) {
        int me = (offs[ee + 1] - offs[ee]) >> 7;     // m-tiles (BM=128)
        int te = me * (HIDDEN / BN1);
        if (!found && bs < at + te) {
            int loc = bs - at;        // te > loc >= 0 implies me > 0
            nt = loc / me;
            mt = loc - nt * me;
            e = ee; found = 1;
        }
        at += te;
    }
    if (!found) return;
    const int m0 = offs[e] + mt * BM;
    const int n0 = nt * BN1;

    const int tid = threadIdx.x;
    const int lane = tid & 63, wid = tid >> 6;
    const int wm = wid >> 1, wn = wid & 1;

    // A staging: 4 gload_lds / thread, pre-swizzled per-lane source
    const unsigned short* asrc[4];
    unsigned aoff[4];
#pragma unroll
    for (int q = 0; q < 4; ++q) {
        int c = q * 256 + tid;          // chunk 0..1023
        int m = c >> 3, kc = c & 7;
        int kcs = kc ^ (m & 7);
        int tok = row_token[m0 + m];    // pads are 0 -> valid row
        asrc[q] = xb + (size_t)tok * D_MODEL + kcs * 8;
        aoff[q] = (unsigned)c * 8u;     // ushort offset
    }
    // B staging: 2 / thread per matrix
    const unsigned short* b1src[2];
    const unsigned short* b3src[2];
    unsigned boff[2];
#pragma unroll
    for (int q = 0; q < 2; ++q) {
        int c = q * 256 + tid;          // chunk 0..511
        int n = c >> 3, kc = c & 7;
        int kcs = kc ^ (n & 7);
        b1src[q] = w1t + ((size_t)e * HIDDEN + n0 + n) * D_MODEL + kcs * 8;
        b3src[q] = w3t + ((size_t)e * HIDDEN + n0 + n) * D_MODEL + kcs * 8;
        boff[q] = (unsigned)c * 8u;
    }

    f32x4 acc1[4][2], acc3[4][2];
    const f32x4 zf = {0.f, 0.f, 0.f, 0.f};
#pragma unroll
    for (int mi = 0; mi < 4; ++mi)
#pragma unroll
        for (int ni = 0; ni < 2; ++ni) { acc1[mi][ni] = zf; acc3[mi][ni] = zf; }

    for (int kt = 0; kt < NT1; ++kt) {
        const int ko = kt * BK;
#pragma unroll
        for (int q = 0; q < 4; ++q) gload_lds16(asrc[q] + ko, &A[aoff[q]]);
#pragma unroll
        for (int q = 0; q < 2; ++q) {
            gload_lds16(b1src[q] + ko, &B1[boff[q]]);
            gload_lds16(b3src[q] + ko, &B3[boff[q]]);
        }
        __syncthreads();
#pragma unroll
        for (int kf = 0; kf < 2; ++kf) {
            bf16x8 a[4], b1f[2], b3f[2];
            int ke = kf * 32 + (lane >> 4) * 8;
#pragma unroll
            for (int mi = 0; mi < 4; ++mi) {
                int m = wm * 64 + mi * 16 + (lane & 15);
                a[mi] = *(const bf16x8*)(&A[m * BK + (ke ^ ((m & 7) * 8))]);
            }
#pragma unroll
            for (int ni = 0; ni < 2; ++ni) {
                int n = wn * 32 + ni * 16 + (lane & 15);
                int eo = n * BK + (ke ^ ((n & 7) * 8));
                b1f[ni] = *(const bf16x8*)(&B1[eo]);
                b3f[ni] = *(const bf16x8*)(&B3[eo]);
            }
#pragma unroll
            for (int mi = 0; mi < 4; ++mi)
#pragma unroll
                for (int ni = 0; ni < 2; ++ni) {
                    acc1[mi][ni] = __builtin_amdgcn_mfma_f32_16x16x32_bf16(a[mi], b1f[ni], acc1[mi][ni], 0, 0, 0);
                    acc3[mi][ni] = __builtin_amdgcn_mfma_f32_16x16x32_bf16(a[mi], b3f[ni], acc3[mi][ni], 0, 0, 0);
                }
        }
        __syncthreads();
    }

    // epilogue: h = silu(acc1)*acc3*w  (pads have weight 0 -> h=0)
#pragma unroll
    for (int mi = 0; mi < 4; ++mi) {
#pragma unroll
        for (int r = 0; r < 4; ++r) {
            int m = wm * 64 + mi * 16 + (lane >> 4) * 4 + r;
            float wgt = row_weight[m0 + m];
            size_t rowbase = (size_t)(m0 + m) * HIDDEN + n0;
#pragma unroll
            for (int ni = 0; ni < 2; ++ni) {
                float v1 = acc1[mi][ni][r], v3 = acc3[mi][ni][r];
                float sv = v1 / (1.f + __expf(-v1));
                int n = wn * 32 + ni * 16 + (lane & 15);
                h[rowbase + n] = f2bf(sv * v3 * wgt);
            }
        }
    }
}

// ---------------- GEMM2: y = h @ w2 (compact grid, padded) ----------------
__global__ __launch_bounds__(256) void k_gemm2(
    const unsigned short* __restrict__ h,    // [Rp][H] bf16
    const unsigned short* __restrict__ w2t,  // [E][D][H] bf16
    const int* __restrict__ offs,
    unsigned short* __restrict__ y)          // [Rp][D] bf16
{
    __shared__ unsigned short A[BM * BK];    // 16 KB
    __shared__ unsigned short B[BN2 * BK];   // 16 KB

    const int b = blockIdx.x;
    const int bs = (b & 7) * (G2_GRID / 8) + (b >> 3);
    int e = 0, mt = 0, nt = 0, found = 0, at = 0;
#pragma unroll
    for (int ee = 0; ee < N_EXP; ++ee) {
        int me = (offs[ee + 1] - offs[ee]) >> 7;
        int te = me * (D_MODEL / BN2);
        if (!found && bs < at + te) {
            int loc = bs - at;
            nt = loc / me;
            mt = loc - nt * me;
            e = ee; found = 1;
        }
        at += te;
    }
    if (!found) return;
    const int m0 = offs[e] + mt * BM;
    const int n0 = nt * BN2;

    const int tid = threadIdx.x;
    const int lane = tid & 63, wid = tid >> 6;
    const int wm = wid >> 1, wn = wid & 1;

    const unsigned short* asrc[4];
    unsigned aoff[4];
#pragma unroll
    for (int q = 0; q < 4; ++q) {
        int c = q * 256 + tid;
        int m = c >> 3, kc = c & 7;
        int kcs = kc ^ (m & 7);
        asrc[q] = h + (size_t)(m0 + m) * HIDDEN + kcs * 8;
        aoff[q] = (unsigned)c * 8u;
    }
    const unsigned short* bsrc[4];
    unsigned boff[4];
#pragma unroll
    for (int q = 0; q < 4; ++q) {
        int c = q * 256 + tid;          // chunk 0..1023 (128 rows x 8)
        int n = c >> 3, kc = c & 7;
        int kcs = kc ^ (n & 7);
        bsrc[q] = w2t + ((size_t)e * D_MODEL + n0 + n) * HIDDEN + kcs * 8;
        boff[q] = (unsigned)c * 8u;
    }

    f32x4 acc[4][4];
    const f32x4 zf = {0.f, 0.f, 0.f, 0.f};
#pragma unroll
    for (int mi = 0; mi < 4; ++mi)
#pragma unroll
        for (int ni = 0; ni < 4; ++ni) acc[mi][ni] = zf;

    for (int kt = 0; kt < NT2; ++kt) {
        const int ko = kt * BK;
#pragma unroll
        for (int q = 0; q < 4; ++q) gload_lds16(asrc[q] + ko, &A[aoff[q]]);
#pragma unroll
        for (int q = 0; q < 4; ++q) gload_lds16(bsrc[q] + ko, &B[boff[q]]);
        __syncthreads();
#pragma unroll
        for (int kf = 0; kf < 2; ++kf) {
            bf16x8 a[4], bfr[4];
            int ke = kf * 32 + (lane >> 4) * 8;
#pragma unroll
            for (int mi = 0; mi < 4; ++mi) {
                int m = wm * 64 + mi * 16 + (lane & 15);
                a[mi] = *(const bf16x8*)(&A[m * BK + (ke ^ ((m & 7) * 8))]);
            }
#pragma unroll
            for (int ni = 0; ni < 4; ++ni) {
                int n = wn * 64 + ni * 16 + (lane & 15);
                bfr[ni] = *(const bf16x8*)(&B[n * BK + (ke ^ ((n & 7) * 8))]);
            }
#pragma unroll
            for (int mi = 0; mi < 4; ++mi)
#pragma unroll
                for (int ni = 0; ni < 4; ++ni)
                    acc[mi][ni] = __builtin_amdgcn_mfma_f32_16x16x32_bf16(a[mi], bfr[ni], acc[mi][ni], 0, 0, 0);
        }
        __syncthreads();
    }

#pragma unroll
    for (int mi = 0; mi < 4; ++mi) {
#pragma unroll
        for (int r = 0; r < 4; ++r) {
            int m = wm * 64 + mi * 16 + (lane >> 4) * 4 + r;
            size_t rowbase = (size_t)(m0 + m) * D_MODEL + n0;
#pragma unroll
            for (int ni = 0; ni < 4; ++ni) {
                int n = wn * 64 + ni * 16 + (lane & 15);
                y[rowbase + n] = f2bf(acc[mi][ni][r]);
            }
        }
    }
}

// ---------------- combine: out[t] = y[pos0] + y[pos1] ----------------
__global__ void k_combine(const unsigned short* __restrict__ y,
                          const int* __restrict__ tok_pos,
                          float* __restrict__ out, int n8) {
    int i = blockIdx.x * blockDim.x + threadIdx.x;
    if (i >= n8) return;
    int t = i >> 7;
    int c = (i & 127) * 8;
    int p0 = tok_pos[2 * t];
    int p1 = tok_pos[2 * t + 1];
    bf16x8 v0 = *(const bf16x8*)(y + (size_t)p0 * D_MODEL + c);
    bf16x8 v1 = *(const bf16x8*)(y + (size_t)p1 * D_MODEL + c);
    float* op = out + (size_t)t * D_MODEL + c;
    float4 o0, o1;
    o0.x = bf2f((unsigned short)v0[0]) + bf2f((unsigned short)v1[0]);
    o0.y = bf2f((unsigned short)v0[1]) + bf2f((unsigned short)v1[1]);
    o0.z = bf2f((unsigned short)v0[2]) + bf2f((unsigned short)v1[2]);
    o0.w = bf2f((unsigned short)v0[3]) + bf2f((unsigned short)v1[3]);
    o1.x = bf2f((unsigned short)v0[4]) + bf2f((unsigned short)v1[4]);
    o1.y = bf2f((unsigned short)v0[5]) + bf2f((unsigned short)v1[5]);
    o1.z = bf2f((unsigned short)v0[6]) + bf2f((unsigned short)v1[6]);
    o1.w = bf2f((unsigned short)v0[7]) + bf2f((unsigned short)v1[7]);
    *(float4*)op = o0;
    *(float4*)(op + 4) = o1;
}

extern "C" void kernel_launch(void* const* d_in, const int* in_sizes, int n_in,
                              void* d_out, int out_size, void* d_ws, size_t ws_size,
                              hipStream_t stream) {
    const float* x  = (const float*)d_in[0];
    const float* wr = (const float*)d_in[1];
    const float* w1 = (const float*)d_in[2];
    const float* w3 = (const float*)d_in[3];
    const float* w2 = (const float*)d_in[4];
    float* out = (float*)d_out;

    const int T = in_sizes[0] / D_MODEL;   // 4096
    const int Rp = T * TOPK + N_EXP * BM;  // padded row bound (9216)

    char* ws = (char*)d_ws;
    size_t o = 0;
    unsigned short* xb  = (unsigned short*)(ws + o); o += (size_t)T * D_MODEL * 2;
    unsigned short* h   = (unsigned short*)(ws + o); o += (size_t)Rp * HIDDEN * 2;
    unsigned short* w1t = (unsigned short*)(ws + o); o += (size_t)N_EXP * D_MODEL * HIDDEN * 2;
    unsigned short* w3t = (unsigned short*)(ws + o); o += (size_t)N_EXP * D_MODEL * HIDDEN * 2;
    unsigned short* w2t = (unsigned short*)(ws + o); o += (size_t)N_EXP * HIDDEN * D_MODEL * 2;
    int*   row_token  = (int*)(ws + o);   o += (size_t)Rp * 4;
    float* row_weight = (float*)(ws + o); o += (size_t)Rp * 4;
    int*   tok_e      = (int*)(ws + o);   o += (size_t)2 * T * 4;
    float* tok_w      = (float*)(ws + o); o += (size_t)2 * T * 4;
    int*   tok_pos    = (int*)(ws + o);   o += (size_t)2 * T * 4;
    int*   counts     = (int*)(ws + o);   o += 16 * 4;
    int*   offs       = (int*)(ws + o);   o += 16 * 4;

    // y aliases w1t (dead after gemm1): needs Rp*D*2 = 18.9 MB <= 33.5 MB
    unsigned short* y = w1t;

    hipMemsetAsync(counts, 0, 16 * 4, stream);
    hipMemsetAsync(row_token, 0, (size_t)Rp * 4, stream);
    hipMemsetAsync(row_weight, 0, (size_t)Rp * 4, stream);

    k_router_cvt<<<(T + 3) / 4, 256, 0, stream>>>(x, wr, xb, tok_e, tok_w, counts, T);

    dim3 gc(512, 24);
    k_cvt3<<<gc, 256, 0, stream>>>(w1, w3, w2, w1t, w3t, w2t);

    k_scan_scatter<<<1, 1024, 0, stream>>>(counts, tok_e, tok_w, offs,
                                           row_token, row_weight, tok_pos, T);

    k_gemm1<<<G1_GRID, 256, 0, stream>>>(xb, w1t, w3t, row_token, row_weight, offs, h);
    k_gemm2<<<G2_GRID, 256, 0, stream>>>(h, w2t, offs, y);

    int n8 = T * D_MODEL / 8;
    k_combine<<<(n8 + 255) / 256, 256, 0, stream>>>(y, tok_pos, out, n8);
}